// Round 11
// baseline (172.916 us; speedup 1.0000x reference)
//
#include <hip/hip_runtime.h>

// VQ-VAE quantizer: h (256,512,32) fp32, embeddings (1024,32) fp32.
// d_out (fp32): quantized_st [4194304] | indices [131072] | loss [131072]
//
// R23: R22 with MAXC reverted 12 -> 8. R22 post-mortem: MAXC bump pushed
// LDS 40448 -> 41472 B, past the 4-blocks/CU boundary (160KB/4 = 40960) ->
// 3 blocks/CU, occupancy 52 -> 22%; scan 46.2 -> 63 == 46.2*4/3 (pure
// occupancy cliff; the sweep-1 cut was drowned). Every list byte is 3x
// leverage through occupancy here. R23 unbundles: keep sweep-1-LDS-only,
// restore MAXC=8 -> LDS 40448 -> 4 blocks/CU.
// Overflow math at MAXC 8 with the M36 threshold: window ~ margin(0.10 sig)
// + E[M64-M36](0.16 sig) ~ 0.26 sig -> lambda ~3 cands/row, P(N>8) ~1% ->
// ~0.3 overflow rows/wave through tail A's exact scan (correctness never
// depends on MAXC). Expected saving: 14 global-tile sweep-1 passes/wave.
//   - sweep1 (18 LDS tiles only): ds_read + 2 MFMA + 8 fmax; pair exchange
//     via 1KB sm -> thr = M36 - fmaf(sar,1.5*2^-17,4e-5) (proven bound:
//     2*delta + E2MAX/2 <= sar*2^-17 + 1.53e-5). M36 <= M64 -> superset.
//   - sweep2 (all 32 tiles): bit-identical recompute, branch-free
//     cm[i] |= (dv>=thr[i]) ? bit : 0; publish once post-sweep.
//   - tails: A overflow exact scan, B bit-exact numpy recheck (pairwise
//     ||f||^2, fmaf chain, fl(fl(f2+e2)-2dot), u64 key argmin).
// History: R12 126 -> R15 111.5 -> R16 107.6 (scan 46.2, occ 52%) ->
//          R17 FAIL -> R18 568 spill -> R20 127 -> R21 200 spill ->
//          R22 121.7 (scan 63, occ 22%: LDS cliff). Fallback: R16 verbatim.

#define EMB_N 1024
#define DIM 32
#define NVEC (256 * 512)
#define NTILES (EMB_N / 16)
#define NT_LDS 36
#define MAXC 8

typedef unsigned long long u64;
typedef unsigned int u32;
typedef unsigned short ushortT;
typedef __attribute__((ext_vector_type(8))) short bf16x8;
typedef __attribute__((ext_vector_type(4))) float f32x4;

__device__ __forceinline__ u32 enc_f32(float x) {
    u32 u = __float_as_uint(x);
    return (u & 0x80000000u) ? ~u : (u | 0x80000000u);  // monotone order-preserving
}
__device__ __forceinline__ ushortT f2bf(float f) {  // RNE fp32->bf16
    u32 u = __float_as_uint(f);
    return (ushortT)((u + 0x7FFFu + ((u >> 16) & 1u)) >> 16);
}
__device__ __forceinline__ u64 shflx_u64(u64 x, int m) {
    int lo = __shfl_xor((int)(u32)x, m);
    int hi = __shfl_xor((int)(x >> 32), m);
    return ((u64)(u32)hi << 32) | (u32)lo;
}

// numpy pairwise ||x||^2, n=32: 8 accumulators stride 8, fixed combine tree
__device__ __forceinline__ float norm2_np(const float* fr) {
    float sq[DIM];
#pragma unroll
    for (int i = 0; i < DIM; ++i) sq[i] = fr[i] * fr[i];
    float r[8];
#pragma unroll
    for (int j = 0; j < 8; ++j)
        r[j] = ((sq[j] + sq[j + 8]) + sq[j + 16]) + sq[j + 24];
    return ((r[0] + r[1]) + (r[2] + r[3])) + ((r[4] + r[5]) + (r[6] + r[7]));
}

// ---- prep: e2 + bf16 B-frag table. frag(nt,lane,j) = bf16(emb[nt*16+(lane&15)][(lane>>4)*8+j])
__global__ __launch_bounds__(256) void prep_kernel(
    const float* __restrict__ emb, float* __restrict__ e2,
    ushortT* __restrict__ bfrag)
{
#pragma clang fp contract(off)
    const int t = blockIdx.x * 256 + threadIdx.x;    // 0..4095
    const int l = t & 63;
    const int row = ((t >> 6) << 4) + (l & 15);
    const int k0 = (l >> 4) * 8;
    const float* ep = emb + (size_t)row * DIM + k0;
    ushortT* dst = bfrag + (size_t)t * 8;
#pragma unroll
    for (int j = 0; j < 8; ++j) dst[j] = f2bf(ep[j]);
    if (t < EMB_N) {
        const float* e = emb + (size_t)t * DIM;
        float tmp[DIM];
#pragma unroll
        for (int i = 0; i < DIM; ++i) tmp[i] = e[i];
        e2[t] = norm2_np(tmp);
    }
}

// sweep 1 body (raw-dot ranking: no e2, no fmaf in hot loop)
#define S1BODY(BEXPR) do {                                                      \
    bf16x8 b = *(const bf16x8*)(BEXPR);                                         \
    f32x4 d0 = __builtin_amdgcn_mfma_f32_16x16x32_bf16(afr0, b, zacc, 0, 0, 0); \
    f32x4 d1 = __builtin_amdgcn_mfma_f32_16x16x32_bf16(afr1, b, zacc, 0, 0, 0); \
    _Pragma("unroll")                                                           \
    for (int r = 0; r < 4; ++r) {                                               \
        bs[r]     = fmaxf(bs[r],     d0[r]);                                    \
        bs[4 + r] = fmaxf(bs[4 + r], d1[r]);                                    \
    }                                                                           \
} while (0)

// sweep 2 body: bit-identical recompute; branch-free mask accumulate.
// K = wave-local tile index 0..31 (nt = 2K+hh); cc decoded at publish.
#define S2BODY(BEXPR, K) do {                                                   \
    bf16x8 b = *(const bf16x8*)(BEXPR);                                         \
    f32x4 d0 = __builtin_amdgcn_mfma_f32_16x16x32_bf16(afr0, b, zacc, 0, 0, 0); \
    f32x4 d1 = __builtin_amdgcn_mfma_f32_16x16x32_bf16(afr1, b, zacc, 0, 0, 0); \
    const u32 bit = 1u << (K);                                                  \
    _Pragma("unroll")                                                           \
    for (int i = 0; i < 8; ++i) {                                               \
        float dv = ((i >> 2) ? d1[i & 3] : d0[i & 3]);                          \
        cm[i] |= (dv >= thr[i]) ? bit : 0u;                                     \
    }                                                                           \
} while (0)

// ---- fused scan: codebook-split wave pairs, mask collect, fused tails ----
__global__ __launch_bounds__(512, 8) void vq_scan(
    const float* __restrict__ h,
    const float* __restrict__ emb,
    const float* __restrict__ e2,
    const ushortT* __restrict__ bfrag,
    float* __restrict__ out_q, float* __restrict__ out_idx,
    float* __restrict__ out_loss)
{
#pragma clang fp contract(off)
    __shared__ __align__(16) ushortT s_b[NT_LDS * 512];   // 36 KB
    __shared__ float   sm[8][32];                         // 1 KB  pair max exchange
    __shared__ u32     lds_cnt[4][32];                    // 512 B per-PAIR lists
    __shared__ ushortT lds_cand[4][32 * MAXC];            // 2 KB  (total 40448B -> 4 blk/CU)

    // cooperative stage of the LDS half: 36 KB = 2304 uint4
    {
        const uint4* src = (const uint4*)bfrag;
        uint4* dst = (uint4*)s_b;
        for (int o = threadIdx.x; o < NT_LDS * 64; o += 512) dst[o] = src[o];
    }

    const int wslot = threadIdx.x >> 6;        // 0..7
    const int pair  = wslot >> 1;              // 0..3
    const int hh    = wslot & 1;               // codebook half
    const int lane  = threadIdx.x & 63;
    const int col16 = lane & 15;
    const int quad  = lane >> 4;
    const size_t row0 = ((size_t)blockIdx.x * 4 + pair) * 32;

    u32*     cnt  = lds_cnt[pair];     // pair-shared
    ushortT* cand = lds_cand[pair];
    if (hh == 0 && lane < 32) cnt[lane] = 0;

    // A-frags for rows row0+col16 (tile0), row0+16+col16 (tile1); fp32 abs-sums
    bf16x8 afr0, afr1;
    float sa0, sa1;
    {
        const float* ap = h + (row0 + col16) * DIM + quad * 8;
        float4 x = *(const float4*)ap, y = *(const float4*)(ap + 4);
        afr0[0]=(short)f2bf(x.x); afr0[1]=(short)f2bf(x.y); afr0[2]=(short)f2bf(x.z); afr0[3]=(short)f2bf(x.w);
        afr0[4]=(short)f2bf(y.x); afr0[5]=(short)f2bf(y.y); afr0[6]=(short)f2bf(y.z); afr0[7]=(short)f2bf(y.w);
        sa0 = fabsf(x.x)+fabsf(x.y)+fabsf(x.z)+fabsf(x.w)+fabsf(y.x)+fabsf(y.y)+fabsf(y.z)+fabsf(y.w);
        const float* bp = ap + 16 * DIM;
        float4 u = *(const float4*)bp, v = *(const float4*)(bp + 4);
        afr1[0]=(short)f2bf(u.x); afr1[1]=(short)f2bf(u.y); afr1[2]=(short)f2bf(u.z); afr1[3]=(short)f2bf(u.w);
        afr1[4]=(short)f2bf(v.x); afr1[5]=(short)f2bf(v.y); afr1[6]=(short)f2bf(v.z); afr1[7]=(short)f2bf(v.w);
        sa1 = fabsf(u.x)+fabsf(u.y)+fabsf(u.z)+fabsf(u.w)+fabsf(v.x)+fabsf(v.y)+fabsf(v.z)+fabsf(v.w);
    }
    sa0 += __shfl_xor(sa0, 16); sa0 += __shfl_xor(sa0, 32);
    sa1 += __shfl_xor(sa1, 16); sa1 += __shfl_xor(sa1, 32);

    __syncthreads();   // LDS table staged + cnt zeroed

    const f32x4 zacc = {0.f, 0.f, 0.f, 0.f};

    // ---- sweep 1 over this wave's LDS tiles ONLY: nt = 2k+hh, k=0..17 ----
    // (Partial max M36 <= M64 -> lower threshold -> superset filter; exact
    //  tail-B recheck preserves bit-exact argmin. Global tiles skipped here.)
    float bs[8];
#pragma unroll
    for (int i = 0; i < 8; ++i) bs[i] = -3.4e38f;
#pragma unroll 2
    for (int k = 0; k < 18; ++k) {             // LDS tiles (nt <= 35)
        const int nt = 2 * k + hh;
        S1BODY(s_b + nt * 512 + lane * 8);
    }
#pragma unroll
    for (int m = 1; m < 16; m <<= 1)
#pragma unroll
        for (int i = 0; i < 8; ++i) bs[i] = fmaxf(bs[i], __shfl_xor(bs[i], m));

    // ---- pair exchange: combined 36-tile max -> per-row threshold ----
    if (col16 == 0) {
#pragma unroll
        for (int i = 0; i < 8; ++i)
            sm[wslot][((i >> 2) << 4) + quad * 4 + (i & 3)] = bs[i];
    }
    __syncthreads();

    float thr[8];
#pragma unroll
    for (int i = 0; i < 8; ++i) {
        const int rloc = ((i >> 2) << 4) + quad * 4 + (i & 3);
        float m = fmaxf(bs[i], sm[wslot ^ 1][rloc]);
        float sar = __shfl((i >> 2) ? sa1 : sa0, quad * 4 + (i & 3));
        // proven bound: 2*delta + E2MAX/2 <= sar*2^-17 + 1.53e-5; 50% headroom
        thr[i] = m - __builtin_fmaf(sar, 0x1.8p-17f, 4.0e-5f);
    }

    // ---- sweep 2: all 32 tiles, bit-identical recompute, mask accumulate ----
    u32 cm[8];
#pragma unroll
    for (int i = 0; i < 8; ++i) cm[i] = 0u;
#pragma unroll 2
    for (int k = 0; k < 18; ++k) {
        const int nt = 2 * k + hh;
        S2BODY(s_b + nt * 512 + lane * 8, k);
    }
#pragma unroll 2
    for (int k = 18; k < 32; ++k) {
        const int nt = 2 * k + hh;
        S2BODY(bfrag + (size_t)nt * 512 + lane * 8, k);
    }

    // ---- publish qualifiers to pair-shared lists (once, post-sweep) ----
    // cc = nt*16 + col16 = (k<<5) + (hh<<4) + col16
#pragma unroll
    for (int i = 0; i < 8; ++i) {
        u32 m = cm[i];
        if (m) {
            const int rloc = ((i >> 2) << 4) + quad * 4 + (i & 3);
            const u32 base = (u32)(hh << 4) + (u32)col16;
            do {
                int k = __ffs(m) - 1; m &= m - 1;
                u32 slot = atomicAdd(&cnt[rloc], 1u);
                if (slot < MAXC)
                    cand[rloc * MAXC + slot] = (ushortT)(((u32)k << 5) + base);
            } while (m);
        }
    }

    __syncthreads();   // pair lists complete

    if (hh != 0) return;   // tails on one wave per pair

    // ---- tail A: overflowed rows (rare) -> wave-cooperative exact scan ----
    u64 ovf = __ballot((lane < 32) && (cnt[lane & 31] > MAXC));
    while (ovf) {
        const int r = (int)(__ffsll((unsigned long long)ovf) - 1);
        ovf &= ovf - 1;
        const float* fp = h + (row0 + r) * DIM;   // wave-uniform row
        float fu[DIM];
#pragma unroll
        for (int i = 0; i < DIM; i += 4) {
            float4 x = *(const float4*)(fp + i);
            fu[i] = x.x; fu[i + 1] = x.y; fu[i + 2] = x.z; fu[i + 3] = x.w;
        }
        const float f2 = norm2_np(fu);
        u64 bk = ~0ull;
        for (int c = lane; c < EMB_N; c += 64) {
            const float* ep = emb + (size_t)c * DIM;
            float a = 0.f;
#pragma unroll
            for (int k = 0; k < DIM; ++k) a = __builtin_fmaf(fu[k], ep[k], a);
            float dd = (f2 + e2[c]) - (2.0f * a);
            u64 key = ((u64)enc_f32(dd) << 32) | (u32)c;
            if (key < bk) bk = key;
        }
#pragma unroll
        for (int m = 1; m < 64; m <<= 1) {
            u64 o = shflx_u64(bk, m);
            if (o < bk) bk = o;
        }
        if (lane == 0) { cand[r * MAXC] = (ushortT)(bk & 1023u); cnt[r] = 1; }
    }

    // ---- tail B: owner lane per row -> recheck + epilogue ----
    if (lane < 32) {
        const int row = (int)row0 + lane;
        const u32 n = cnt[lane];
        const float* f = h + (size_t)row * DIM;
        float fr[DIM];
#pragma unroll
        for (int i = 0; i < DIM; i += 4) {
            float4 x = *(const float4*)(f + i);
            fr[i] = x.x; fr[i + 1] = x.y; fr[i + 2] = x.z; fr[i + 3] = x.w;
        }
        int bidx;
        if (n == 1) {
            bidx = (int)cand[lane * MAXC];       // sole certified qualifier
        } else {
            const float f2 = norm2_np(fr);
            u64 best = ~0ull;
            for (u32 j = 0; j < n; ++j) {
                const u32 c = (u32)cand[lane * MAXC + j];
                const float* ep = emb + (size_t)c * DIM;
                float a = 0.f;
#pragma unroll
                for (int k = 0; k < DIM; ++k) a = __builtin_fmaf(fr[k], ep[k], a);  // BLAS chain
                float dd = (f2 + e2[c]) - (2.0f * a);     // exact numpy formula
                u64 key = ((u64)enc_f32(dd) << 32) | c;
                if (key < best) best = key;
            }
            bidx = (int)(best & 0xFFFFFFFFu);
        }

        const float* qv = emb + (size_t)bidx * DIM;
        float ps = 0.f;
#pragma unroll
        for (int i = 0; i < DIM; i += 4) {
            float4 qx; qx.x = qv[i]; qx.y = qv[i+1]; qx.z = qv[i+2]; qx.w = qv[i+3];
            float dx = qx.x - fr[i], dy = qx.y - fr[i+1], dz = qx.z - fr[i+2], dw = qx.w - fr[i+3];
            ps += dx * dx; ps += dy * dy; ps += dz * dz; ps += dw * dw;
            float4 o;
            o.x = fr[i]     + (qx.x - fr[i]);
            o.y = fr[i + 1] + (qx.y - fr[i + 1]);
            o.z = fr[i + 2] + (qx.z - fr[i + 2]);
            o.w = fr[i + 3] + (qx.w - fr[i + 3]);
            *(float4*)(out_q + (size_t)row * DIM + i) = o;
        }
        float m = ps * (1.0f / DIM);
        out_idx[row]  = (float)bidx;
        out_loss[row] = m * 0.1f + m * 0.1f;
    }
}

// ---------- fallback (R3-style) if workspace too small ----------
__global__ void e2_kernel(const float* __restrict__ emb, float* __restrict__ e2) {
#pragma clang fp contract(off)
    int c = blockIdx.x * blockDim.x + threadIdx.x;
    if (c >= EMB_N) return;
    const float* e = emb + (size_t)c * DIM;
    float tmp[DIM];
#pragma unroll
    for (int i = 0; i < DIM; ++i) tmp[i] = e[i];
    e2[c] = norm2_np(tmp);
}

__global__ __launch_bounds__(256) void vq_kernel(
    const float* __restrict__ h, const float* __restrict__ emb,
    const float* __restrict__ e2, float* __restrict__ out_q,
    float* __restrict__ out_idx, float* __restrict__ out_loss)
{
#pragma clang fp contract(off)
    const int v = blockIdx.x * blockDim.x + threadIdx.x;
    const float* f = h + (size_t)v * DIM;
    float fr[DIM];
#pragma unroll
    for (int i = 0; i < DIM; i += 4) {
        float4 x = *(const float4*)(f + i);
        fr[i] = x.x; fr[i + 1] = x.y; fr[i + 2] = x.z; fr[i + 3] = x.w;
    }
    const float f2 = norm2_np(fr);
    float best = 3.4e38f; int bidx = 0;
#pragma unroll 1
    for (int c = 0; c < EMB_N; ++c) {
        const float* e = emb + (size_t)c * DIM;
        float a0 = 0.f;
#pragma unroll
        for (int k = 0; k < DIM; ++k) a0 = __builtin_fmaf(fr[k], e[k], a0);
        float d0 = (f2 + e2[c]) - (2.0f * a0);
        if (d0 < best) { best = d0; bidx = c; }
    }
    const float* q = emb + (size_t)bidx * DIM;
    float ps = 0.f;
#pragma unroll
    for (int i = 0; i < DIM; i += 4) {
        float4 qx; qx.x = q[i]; qx.y = q[i+1]; qx.z = q[i+2]; qx.w = q[i+3];
        float dx = qx.x - fr[i], dy = qx.y - fr[i+1], dz = qx.z - fr[i+2], dw = qx.w - fr[i+3];
        ps += dx * dx; ps += dy * dy; ps += dz * dz; ps += dw * dw;
        float4 o;
        o.x = fr[i] + (qx.x - fr[i]); o.y = fr[i+1] + (qx.y - fr[i+1]);
        o.z = fr[i+2] + (qx.z - fr[i+2]); o.w = fr[i+3] + (qx.w - fr[i+3]);
        *(float4*)(out_q + (size_t)v * DIM + i) = o;
    }
    float m = ps * (1.0f / DIM);
    out_idx[v]  = (float)bidx;
    out_loss[v] = m * 0.1f + m * 0.1f;
}

extern "C" void kernel_launch(void* const* d_in, const int* in_sizes, int n_in,
                              void* d_out, int out_size, void* d_ws, size_t ws_size,
                              hipStream_t stream) {
    const float* h   = (const float*)d_in[0];
    const float* emb = (const float*)d_in[1];
    float* out = (float*)d_out;
    float* out_q    = out;                               // 4194304
    float* out_idx  = out + (size_t)NVEC * DIM;          // 131072
    float* out_loss = out + (size_t)NVEC * DIM + NVEC;   // 131072

    // ws layout: e2 4KB | bfrag 64KB
    float*   e2    = (float*)d_ws;
    ushortT* bfrag = (ushortT*)((char*)d_ws + 4096);
    const size_t need = 4096 + (size_t)EMB_N * DIM * sizeof(ushortT);

    if (ws_size >= need) {
        prep_kernel<<<16, 256, 0, stream>>>(emb, e2, bfrag);
        vq_scan<<<1024, 512, 0, stream>>>(h, emb, e2, bfrag,
                                          out_q, out_idx, out_loss);
    } else {
        e2_kernel<<<EMB_N / 256, 256, 0, stream>>>(emb, e2);
        vq_kernel<<<NVEC / 256, 256, 0, stream>>>(h, emb, e2, out_q, out_idx, out_loss);
    }
}

// Round 12
// 109.134 us; speedup vs baseline: 1.5844x; 1.5844x over previous
//
#include <hip/hip_runtime.h>

// VQ-VAE quantizer: h (256,512,32) fp32, embeddings (1024,32) fp32.
// d_out (fp32): quantized_st [4194304] | indices [131072] | loss [131072]
//
// R24: R16's two-sweep certified filter with the FULL 64KB codebook table
// in LDS at 1024-thread blocks.
// Post-mortems: R23 proved the sweep-1-LDS-only cut toxic (M36 window ->
// candidate inflation -> frequent tail-A exact scans -> occ 28%, scan 112);
// R16's full-codebook sweep-1 semantics restored VERBATIM. The remaining
// structural cost in R16: the 28-tile global segment streams 56KB/wave
// through L1 across both sweeps (~460MB chip-wide ~ 12us of L1 cycles +
// vmcnt gaps). R11's full-table-LDS failed only because 256-thr blocks
// capped occupancy (2 blk/CU x 4 waves = 8 waves/CU). Fix occupancy side:
//   - block 1024 thr = 16 waves = 8 pairs; grid 512; 2 blocks/CU ->
//     32 waves/CU (same nominal occupancy as R16's 4x512 config).
//   - dynamic LDS 72704B: 64KB table + 2KB sm + 1KB cnt + 4KB cand
//     (2 x 72.7KB = 145KB <= 160KB/CU). hipFuncSetAttribute for >64KB.
//   - hot loop PURE LDS: zero global loads, zero vmcnt waits in sweeps.
//   - everything else bit-identical to R16: full sweep-1 (wave pair covers
//     all 64 tiles, nt=2k+hh), pair max exchange, thr = M64 -
//     fmaf(sar,1.5*2^-17,4e-5) (proven: 2*delta + E2MAX/2 <= sar*2^-17 +
//     1.53e-5), branch-free sweep-2 mask collect, MAXC=8 lists, tail A
//     overflow exact scan, tail B bit-exact numpy recheck.
// History: R12 126 -> R15 111.5 -> R16 107.6 (scan 46.2, occ 52%) ->
//          R17-R21 single-sweep line dead (spill/serial) -> R22 121.7
//          (LDS cliff) -> R23 172.9 (M36 cut toxic, occ 28%).
// Fallback if occ ~25% (1 blk/CU) or scan >= 46: R16 verbatim, terminal.

#define EMB_N 1024
#define DIM 32
#define NVEC (256 * 512)
#define NTILES (EMB_N / 16)
#define MAXC 8
#define SMEM_BYTES 72704

typedef unsigned long long u64;
typedef unsigned int u32;
typedef unsigned short ushortT;
typedef __attribute__((ext_vector_type(8))) short bf16x8;
typedef __attribute__((ext_vector_type(4))) float f32x4;

__device__ __forceinline__ u32 enc_f32(float x) {
    u32 u = __float_as_uint(x);
    return (u & 0x80000000u) ? ~u : (u | 0x80000000u);  // monotone order-preserving
}
__device__ __forceinline__ ushortT f2bf(float f) {  // RNE fp32->bf16
    u32 u = __float_as_uint(f);
    return (ushortT)((u + 0x7FFFu + ((u >> 16) & 1u)) >> 16);
}
__device__ __forceinline__ u64 shflx_u64(u64 x, int m) {
    int lo = __shfl_xor((int)(u32)x, m);
    int hi = __shfl_xor((int)(x >> 32), m);
    return ((u64)(u32)hi << 32) | (u32)lo;
}

// numpy pairwise ||x||^2, n=32: 8 accumulators stride 8, fixed combine tree
__device__ __forceinline__ float norm2_np(const float* fr) {
    float sq[DIM];
#pragma unroll
    for (int i = 0; i < DIM; ++i) sq[i] = fr[i] * fr[i];
    float r[8];
#pragma unroll
    for (int j = 0; j < 8; ++j)
        r[j] = ((sq[j] + sq[j + 8]) + sq[j + 16]) + sq[j + 24];
    return ((r[0] + r[1]) + (r[2] + r[3])) + ((r[4] + r[5]) + (r[6] + r[7]));
}

// ---- prep: e2 + bf16 B-frag table. frag(nt,lane,j) = bf16(emb[nt*16+(lane&15)][(lane>>4)*8+j])
__global__ __launch_bounds__(256) void prep_kernel(
    const float* __restrict__ emb, float* __restrict__ e2,
    ushortT* __restrict__ bfrag)
{
#pragma clang fp contract(off)
    const int t = blockIdx.x * 256 + threadIdx.x;    // 0..4095
    const int l = t & 63;
    const int row = ((t >> 6) << 4) + (l & 15);
    const int k0 = (l >> 4) * 8;
    const float* ep = emb + (size_t)row * DIM + k0;
    ushortT* dst = bfrag + (size_t)t * 8;
#pragma unroll
    for (int j = 0; j < 8; ++j) dst[j] = f2bf(ep[j]);
    if (t < EMB_N) {
        const float* e = emb + (size_t)t * DIM;
        float tmp[DIM];
#pragma unroll
        for (int i = 0; i < DIM; ++i) tmp[i] = e[i];
        e2[t] = norm2_np(tmp);
    }
}

// sweep 1 body (raw-dot ranking: no e2, no fmaf in hot loop)
#define S1BODY(BEXPR) do {                                                      \
    bf16x8 b = *(const bf16x8*)(BEXPR);                                         \
    f32x4 d0 = __builtin_amdgcn_mfma_f32_16x16x32_bf16(afr0, b, zacc, 0, 0, 0); \
    f32x4 d1 = __builtin_amdgcn_mfma_f32_16x16x32_bf16(afr1, b, zacc, 0, 0, 0); \
    _Pragma("unroll")                                                           \
    for (int r = 0; r < 4; ++r) {                                               \
        bs[r]     = fmaxf(bs[r],     d0[r]);                                    \
        bs[4 + r] = fmaxf(bs[4 + r], d1[r]);                                    \
    }                                                                           \
} while (0)

// sweep 2 body: bit-identical recompute; branch-free mask accumulate.
// K = wave-local tile index 0..31 (nt = 2K+hh); cc decoded at publish.
#define S2BODY(BEXPR, K) do {                                                   \
    bf16x8 b = *(const bf16x8*)(BEXPR);                                         \
    f32x4 d0 = __builtin_amdgcn_mfma_f32_16x16x32_bf16(afr0, b, zacc, 0, 0, 0); \
    f32x4 d1 = __builtin_amdgcn_mfma_f32_16x16x32_bf16(afr1, b, zacc, 0, 0, 0); \
    const u32 bit = 1u << (K);                                                  \
    _Pragma("unroll")                                                           \
    for (int i = 0; i < 8; ++i) {                                               \
        float dv = ((i >> 2) ? d1[i & 3] : d0[i & 3]);                          \
        cm[i] |= (dv >= thr[i]) ? bit : 0u;                                     \
    }                                                                           \
} while (0)

// ---- fused scan: full-LDS table, codebook-split wave pairs, fused tails ----
__global__ __launch_bounds__(1024, 8) void vq_scan(
    const float* __restrict__ h,
    const float* __restrict__ emb,
    const float* __restrict__ e2,
    const ushortT* __restrict__ bfrag,
    float* __restrict__ out_q, float* __restrict__ out_idx,
    float* __restrict__ out_loss)
{
#pragma clang fp contract(off)
    extern __shared__ __align__(16) char smem_raw[];
    ushortT* s_b      = (ushortT*)smem_raw;                 // 64 KB: full table
    float*   sm       = (float*)(smem_raw + 65536);         // 2 KB: 16 wslots x 32
    u32*     lds_cnt  = (u32*)(smem_raw + 67584);           // 1 KB: 8 pairs x 32
    ushortT* lds_cand = (ushortT*)(smem_raw + 68608);       // 4 KB: 8 x 32 x MAXC

    // cooperative stage of the FULL table: 64 KB = 4096 uint4
    {
        const uint4* src = (const uint4*)bfrag;
        uint4* dst = (uint4*)s_b;
#pragma unroll
        for (int o = threadIdx.x; o < 4096; o += 1024) dst[o] = src[o];
    }

    const int wslot = threadIdx.x >> 6;        // 0..15
    const int pair  = wslot >> 1;              // 0..7
    const int hh    = wslot & 1;               // codebook half
    const int lane  = threadIdx.x & 63;
    const int col16 = lane & 15;
    const int quad  = lane >> 4;
    const size_t row0 = ((size_t)blockIdx.x * 8 + pair) * 32;

    u32*     cnt  = lds_cnt + pair * 32;       // pair-shared
    ushortT* cand = lds_cand + pair * 32 * MAXC;
    if (hh == 0 && lane < 32) cnt[lane] = 0;

    // A-frags for rows row0+col16 (tile0), row0+16+col16 (tile1); fp32 abs-sums
    bf16x8 afr0, afr1;
    float sa0, sa1;
    {
        const float* ap = h + (row0 + col16) * DIM + quad * 8;
        float4 x = *(const float4*)ap, y = *(const float4*)(ap + 4);
        afr0[0]=(short)f2bf(x.x); afr0[1]=(short)f2bf(x.y); afr0[2]=(short)f2bf(x.z); afr0[3]=(short)f2bf(x.w);
        afr0[4]=(short)f2bf(y.x); afr0[5]=(short)f2bf(y.y); afr0[6]=(short)f2bf(y.z); afr0[7]=(short)f2bf(y.w);
        sa0 = fabsf(x.x)+fabsf(x.y)+fabsf(x.z)+fabsf(x.w)+fabsf(y.x)+fabsf(y.y)+fabsf(y.z)+fabsf(y.w);
        const float* bp = ap + 16 * DIM;
        float4 u = *(const float4*)bp, v = *(const float4*)(bp + 4);
        afr1[0]=(short)f2bf(u.x); afr1[1]=(short)f2bf(u.y); afr1[2]=(short)f2bf(u.z); afr1[3]=(short)f2bf(u.w);
        afr1[4]=(short)f2bf(v.x); afr1[5]=(short)f2bf(v.y); afr1[6]=(short)f2bf(v.z); afr1[7]=(short)f2bf(v.w);
        sa1 = fabsf(u.x)+fabsf(u.y)+fabsf(u.z)+fabsf(u.w)+fabsf(v.x)+fabsf(v.y)+fabsf(v.z)+fabsf(v.w);
    }
    sa0 += __shfl_xor(sa0, 16); sa0 += __shfl_xor(sa0, 32);
    sa1 += __shfl_xor(sa1, 16); sa1 += __shfl_xor(sa1, 32);

    __syncthreads();   // full table staged + cnt zeroed

    const f32x4 zacc = {0.f, 0.f, 0.f, 0.f};

    // ---- sweep 1 over this wave's half (ALL from LDS): nt = 2k+hh ----
    float bs[8];
#pragma unroll
    for (int i = 0; i < 8; ++i) bs[i] = -3.4e38f;
#pragma unroll 2
    for (int k = 0; k < 32; ++k) {
        const int nt = 2 * k + hh;
        S1BODY(s_b + nt * 512 + lane * 8);
    }
#pragma unroll
    for (int m = 1; m < 16; m <<= 1)
#pragma unroll
        for (int i = 0; i < 8; ++i) bs[i] = fmaxf(bs[i], __shfl_xor(bs[i], m));

    // ---- pair exchange: combined full-codebook max -> per-row threshold ----
    if (col16 == 0) {
#pragma unroll
        for (int i = 0; i < 8; ++i)
            sm[wslot * 32 + ((i >> 2) << 4) + quad * 4 + (i & 3)] = bs[i];
    }
    __syncthreads();

    float thr[8];
#pragma unroll
    for (int i = 0; i < 8; ++i) {
        const int rloc = ((i >> 2) << 4) + quad * 4 + (i & 3);
        float m = fmaxf(bs[i], sm[(wslot ^ 1) * 32 + rloc]);
        float sar = __shfl((i >> 2) ? sa1 : sa0, quad * 4 + (i & 3));
        // proven bound: 2*delta + E2MAX/2 <= sar*2^-17 + 1.53e-5; 50% headroom
        thr[i] = m - __builtin_fmaf(sar, 0x1.8p-17f, 4.0e-5f);
    }

    // ---- sweep 2: bit-identical recompute (ALL from LDS), mask accumulate ----
    u32 cm[8];
#pragma unroll
    for (int i = 0; i < 8; ++i) cm[i] = 0u;
#pragma unroll 2
    for (int k = 0; k < 32; ++k) {
        const int nt = 2 * k + hh;
        S2BODY(s_b + nt * 512 + lane * 8, k);
    }

    // ---- publish qualifiers to pair-shared lists (once, post-sweep) ----
    // cc = nt*16 + col16 = (k<<5) + (hh<<4) + col16
#pragma unroll
    for (int i = 0; i < 8; ++i) {
        u32 m = cm[i];
        if (m) {
            const int rloc = ((i >> 2) << 4) + quad * 4 + (i & 3);
            const u32 base = (u32)(hh << 4) + (u32)col16;
            do {
                int k = __ffs(m) - 1; m &= m - 1;
                u32 slot = atomicAdd(&cnt[rloc], 1u);
                if (slot < MAXC)
                    cand[rloc * MAXC + slot] = (ushortT)(((u32)k << 5) + base);
            } while (m);
        }
    }

    __syncthreads();   // pair lists complete

    if (hh != 0) return;   // tails on one wave per pair

    // ---- tail A: overflowed rows (rare) -> wave-cooperative exact scan ----
    u64 ovf = __ballot((lane < 32) && (cnt[lane & 31] > MAXC));
    while (ovf) {
        const int r = (int)(__ffsll((unsigned long long)ovf) - 1);
        ovf &= ovf - 1;
        const float* fp = h + (row0 + r) * DIM;   // wave-uniform row
        float fu[DIM];
#pragma unroll
        for (int i = 0; i < DIM; i += 4) {
            float4 x = *(const float4*)(fp + i);
            fu[i] = x.x; fu[i + 1] = x.y; fu[i + 2] = x.z; fu[i + 3] = x.w;
        }
        const float f2 = norm2_np(fu);
        u64 bk = ~0ull;
        for (int c = lane; c < EMB_N; c += 64) {
            const float* ep = emb + (size_t)c * DIM;
            float a = 0.f;
#pragma unroll
            for (int k = 0; k < DIM; ++k) a = __builtin_fmaf(fu[k], ep[k], a);
            float dd = (f2 + e2[c]) - (2.0f * a);
            u64 key = ((u64)enc_f32(dd) << 32) | (u32)c;
            if (key < bk) bk = key;
        }
#pragma unroll
        for (int m = 1; m < 64; m <<= 1) {
            u64 o = shflx_u64(bk, m);
            if (o < bk) bk = o;
        }
        if (lane == 0) { cand[r * MAXC] = (ushortT)(bk & 1023u); cnt[r] = 1; }
    }

    // ---- tail B: owner lane per row -> recheck + epilogue ----
    if (lane < 32) {
        const int row = (int)row0 + lane;
        const u32 n = cnt[lane];
        const float* f = h + (size_t)row * DIM;
        float fr[DIM];
#pragma unroll
        for (int i = 0; i < DIM; i += 4) {
            float4 x = *(const float4*)(f + i);
            fr[i] = x.x; fr[i + 1] = x.y; fr[i + 2] = x.z; fr[i + 3] = x.w;
        }
        int bidx;
        if (n == 1) {
            bidx = (int)cand[lane * MAXC];       // sole certified qualifier
        } else {
            const float f2 = norm2_np(fr);
            u64 best = ~0ull;
            for (u32 j = 0; j < n; ++j) {
                const u32 c = (u32)cand[lane * MAXC + j];
                const float* ep = emb + (size_t)c * DIM;
                float a = 0.f;
#pragma unroll
                for (int k = 0; k < DIM; ++k) a = __builtin_fmaf(fr[k], ep[k], a);  // BLAS chain
                float dd = (f2 + e2[c]) - (2.0f * a);     // exact numpy formula
                u64 key = ((u64)enc_f32(dd) << 32) | c;
                if (key < best) best = key;
            }
            bidx = (int)(best & 0xFFFFFFFFu);
        }

        const float* qv = emb + (size_t)bidx * DIM;
        float ps = 0.f;
#pragma unroll
        for (int i = 0; i < DIM; i += 4) {
            float4 qx; qx.x = qv[i]; qx.y = qv[i+1]; qx.z = qv[i+2]; qx.w = qv[i+3];
            float dx = qx.x - fr[i], dy = qx.y - fr[i+1], dz = qx.z - fr[i+2], dw = qx.w - fr[i+3];
            ps += dx * dx; ps += dy * dy; ps += dz * dz; ps += dw * dw;
            float4 o;
            o.x = fr[i]     + (qx.x - fr[i]);
            o.y = fr[i + 1] + (qx.y - fr[i + 1]);
            o.z = fr[i + 2] + (qx.z - fr[i + 2]);
            o.w = fr[i + 3] + (qx.w - fr[i + 3]);
            *(float4*)(out_q + (size_t)row * DIM + i) = o;
        }
        float m = ps * (1.0f / DIM);
        out_idx[row]  = (float)bidx;
        out_loss[row] = m * 0.1f + m * 0.1f;
    }
}

// ---------- fallback (R3-style) if workspace too small ----------
__global__ void e2_kernel(const float* __restrict__ emb, float* __restrict__ e2) {
#pragma clang fp contract(off)
    int c = blockIdx.x * blockDim.x + threadIdx.x;
    if (c >= EMB_N) return;
    const float* e = emb + (size_t)c * DIM;
    float tmp[DIM];
#pragma unroll
    for (int i = 0; i < DIM; ++i) tmp[i] = e[i];
    e2[c] = norm2_np(tmp);
}

__global__ __launch_bounds__(256) void vq_kernel(
    const float* __restrict__ h, const float* __restrict__ emb,
    const float* __restrict__ e2, float* __restrict__ out_q,
    float* __restrict__ out_idx, float* __restrict__ out_loss)
{
#pragma clang fp contract(off)
    const int v = blockIdx.x * blockDim.x + threadIdx.x;
    const float* f = h + (size_t)v * DIM;
    float fr[DIM];
#pragma unroll
    for (int i = 0; i < DIM; i += 4) {
        float4 x = *(const float4*)(f + i);
        fr[i] = x.x; fr[i + 1] = x.y; fr[i + 2] = x.z; fr[i + 3] = x.w;
    }
    const float f2 = norm2_np(fr);
    float best = 3.4e38f; int bidx = 0;
#pragma unroll 1
    for (int c = 0; c < EMB_N; ++c) {
        const float* e = emb + (size_t)c * DIM;
        float a0 = 0.f;
#pragma unroll
        for (int k = 0; k < DIM; ++k) a0 = __builtin_fmaf(fr[k], e[k], a0);
        float d0 = (f2 + e2[c]) - (2.0f * a0);
        if (d0 < best) { best = d0; bidx = c; }
    }
    const float* q = emb + (size_t)bidx * DIM;
    float ps = 0.f;
#pragma unroll
    for (int i = 0; i < DIM; i += 4) {
        float4 qx; qx.x = q[i]; qx.y = q[i+1]; qx.z = q[i+2]; qx.w = q[i+3];
        float dx = qx.x - fr[i], dy = qx.y - fr[i+1], dz = qx.z - fr[i+2], dw = qx.w - fr[i+3];
        ps += dx * dx; ps += dy * dy; ps += dz * dz; ps += dw * dw;
        float4 o;
        o.x = fr[i] + (qx.x - fr[i]); o.y = fr[i+1] + (qx.y - fr[i+1]);
        o.z = fr[i+2] + (qx.z - fr[i+2]); o.w = fr[i+3] + (qx.w - fr[i+3]);
        *(float4*)(out_q + (size_t)v * DIM + i) = o;
    }
    float m = ps * (1.0f / DIM);
    out_idx[v]  = (float)bidx;
    out_loss[v] = m * 0.1f + m * 0.1f;
}

extern "C" void kernel_launch(void* const* d_in, const int* in_sizes, int n_in,
                              void* d_out, int out_size, void* d_ws, size_t ws_size,
                              hipStream_t stream) {
    const float* h   = (const float*)d_in[0];
    const float* emb = (const float*)d_in[1];
    float* out = (float*)d_out;
    float* out_q    = out;                               // 4194304
    float* out_idx  = out + (size_t)NVEC * DIM;          // 131072
    float* out_loss = out + (size_t)NVEC * DIM + NVEC;   // 131072

    // ws layout: e2 4KB | bfrag 64KB
    float*   e2    = (float*)d_ws;
    ushortT* bfrag = (ushortT*)((char*)d_ws + 4096);
    const size_t need = 4096 + (size_t)EMB_N * DIM * sizeof(ushortT);

    if (ws_size >= need) {
        static bool attr_set = false;
        if (!attr_set) {
            (void)hipFuncSetAttribute((const void*)vq_scan,
                hipFuncAttributeMaxDynamicSharedMemorySize, SMEM_BYTES);
            attr_set = true;
        }
        prep_kernel<<<16, 256, 0, stream>>>(emb, e2, bfrag);
        vq_scan<<<512, 1024, SMEM_BYTES, stream>>>(h, emb, e2, bfrag,
                                                   out_q, out_idx, out_loss);
    } else {
        e2_kernel<<<EMB_N / 256, 256, 0, stream>>>(emb, e2);
        vq_kernel<<<NVEC / 256, 256, 0, stream>>>(h, emb, e2, out_q, out_idx, out_loss);
    }
}